// Round 10
// baseline (165.030 us; speedup 1.0000x reference)
//
#include <hip/hip_runtime.h>
#include <hip/hip_bf16.h>
#include <math.h>

#define B_  2
#define CIN 64
#define COUT 64
#define H_  192
#define W_  192
#define G_  2
#define KK_ 9
#define CG_ 32
#define HW_ (H_*W_)
#define PIX 64            // pixels per block (x-contiguous)
#define XT_ (W_/PIX)      // 3 x-tiles per row
#define NB_NHWC (B_ * (HW_ / 64))        // 1152
#define NB_WT   ((18*4*64*8 + 18*2*64*8) / 256)   // 216

typedef __attribute__((ext_vector_type(8))) short bf16x8;
typedef __attribute__((ext_vector_type(4))) float f32x4;

// round-to-nearest-even fp32 -> bf16 bit pattern (scalar path)
static __device__ __forceinline__ short f2bf(float f) {
    unsigned u = __builtin_bit_cast(unsigned, f);
    u = (u + 0x7fffu + ((u >> 16) & 1u)) >> 16;
    return (short)u;
}
static __device__ __forceinline__ float bf2f(short s) {
    unsigned u = ((unsigned)(unsigned short)s) << 16;
    return __builtin_bit_cast(float, u);
}
// packed fp32x2 -> bf16x2 (v_cvt_pk_bf16_f32 on gfx950)
static __device__ __forceinline__ short2 pk2bf(float lo, float hi) {
    float2 f; f.x = lo; f.y = hi;
    __hip_bfloat162 hh = __float22bfloat162_rn(f);
    short2 r;
    __builtin_memcpy(&r, &hh, sizeof(r));
    return r;
}

// ---------------------------------------------------------------------------
// Kernel A: prep — NCHW->NHWC bf16 transform (blocks < NB_NHWC) + weight pack.
// ---------------------------------------------------------------------------
__global__ __launch_bounds__(256)
void prep_kernel(const float* __restrict__ in,
                 const float* __restrict__ weight,
                 const float* __restrict__ sem_w,
                 const float* __restrict__ m2_w,
                 short* __restrict__ inpT,
                 short* __restrict__ wbm,
                 short* __restrict__ wbs) {
    __shared__ float t[64][65];
    const int tid = threadIdx.x;
    const int bid = blockIdx.x;
    if (bid < NB_NHWC) {
        const int b = bid / (HW_ / 64);
        const int pix0 = (bid % (HW_ / 64)) * 64;
        const float* src = in + (size_t)b * CIN * HW_ + pix0;
        const int c0 = (tid >> 6) * 16;
        const int p  = tid & 63;
        #pragma unroll
        for (int i = 0; i < 16; ++i)
            t[c0 + i][p] = src[(size_t)(c0 + i) * HW_ + p];
        __syncthreads();
        short* dst = inpT + ((size_t)b * HW_ + pix0) * 64;
        #pragma unroll
        for (int i = 0; i < 2; ++i) {
            int item = i * 256 + tid;
            int pp = item >> 3, oct = item & 7;
            bf16x8 v;
            #pragma unroll
            for (int j = 0; j < 8; j += 2) {
                short2 ss = pk2bf(t[oct * 8 + j][pp], t[oct * 8 + j + 1][pp]);
                v[j] = ss.x; v[j + 1] = ss.y;
            }
            *(bf16x8*)&dst[pp * 64 + oct * 8] = v;
        }
        return;
    }
    int i = (bid - NB_NHWC) * 256 + tid;
    if (i < 18 * 4 * 64 * 8) {
        int j = i & 7, lane = (i >> 3) & 63, nt = (i >> 9) & 3, gk = i >> 11;
        int n = lane & 15, q = lane >> 4;
        int o = nt * 16 + n;
        int g = gk / 9, k = gk - g * 9;
        int cin = g * CG_ + q * 8 + j;
        wbm[i] = f2bf(weight[(o * CIN + cin) * 9 + k]);
        return;
    }
    int ii = i - 18 * 4 * 64 * 8;
    if (ii >= 18 * 2 * 64 * 8) return;
    int j = ii & 7, lane = (ii >> 3) & 63, nt = (ii >> 9) & 1, s = ii >> 10;
    int t_ = s >> 1, h = s & 1;
    int n = lane & 15, q = lane >> 4;
    int o = nt * 16 + n;
    int c = h * 32 + q * 8 + j;
    float v = 0.f;
    if (o < 18)      v = sem_w[(o * CIN + c) * 9 + t_];
    else if (o < 27) v = m2_w[((o - 18) * CIN + c) * 9 + t_];
    wbs[ii] = f2bf(v);
}

// ---------------------------------------------------------------------------
// one main-conv K-step. NAMED accumulators macc0..macc3 — do not convert to
// an indexed array (miscompiles on this toolchain).
// ---------------------------------------------------------------------------
#define MBODY(GK, GOFF, WV) { \
    float2 XY = pxy[(GK) * 64 + (WV) * 16 + n]; \
    float dm  = dml[(GK) * 64 + (WV) * 16 + n]; \
    float Y = XY.x, X = XY.y; \
    float y0f = floorf(Y), x0f = floorf(X); \
    int y0 = (int)y0f, x0 = (int)x0f; \
    float ly = Y - y0f, lx = X - x0f; \
    int y1 = y0 + 1, x1 = x0 + 1; \
    bool vy0 = (y0 >= 0 && y0 < H_), vy1 = (y1 >= 0 && y1 < H_); \
    bool vx0 = (x0 >= 0 && x0 < W_), vx1 = (x1 >= 0 && x1 < W_); \
    float w00 = (vy0 && vx0) ? (1.f - ly) * (1.f - lx) * dm : 0.f; \
    float w01 = (vy0 && vx1) ? (1.f - ly) * lx * dm : 0.f; \
    float w10 = (vy1 && vx0) ? ly * (1.f - lx) * dm : 0.f; \
    float w11 = (vy1 && vx1) ? ly * lx * dm : 0.f; \
    int yc0 = min(max(y0, 0), H_ - 1), yc1 = min(max(y1, 0), H_ - 1); \
    int xc0 = min(max(x0, 0), W_ - 1), xc1 = min(max(x1, 0), W_ - 1); \
    const short* pb = inpT + (size_t)b * HW_ * 64 + (GOFF) + q * 8; \
    bf16x8 c00 = *(const bf16x8*)(pb + (size_t)(yc0 * W_ + xc0) * 64); \
    bf16x8 c01 = *(const bf16x8*)(pb + (size_t)(yc0 * W_ + xc1) * 64); \
    bf16x8 c10 = *(const bf16x8*)(pb + (size_t)(yc1 * W_ + xc0) * 64); \
    bf16x8 c11 = *(const bf16x8*)(pb + (size_t)(yc1 * W_ + xc1) * 64); \
    bf16x8 a; \
    _Pragma("unroll") \
    for (int j = 0; j < 8; j += 2) { \
        float s0 = w00 * bf2f(c00[j])   + w01 * bf2f(c01[j]) \
                 + w10 * bf2f(c10[j])   + w11 * bf2f(c11[j]); \
        float s1 = w00 * bf2f(c00[j+1]) + w01 * bf2f(c01[j+1]) \
                 + w10 * bf2f(c10[j+1]) + w11 * bf2f(c11[j+1]); \
        short2 ss = pk2bf(s0, s1); \
        a[j] = ss.x; a[j + 1] = ss.y; \
    } \
    bf16x8 wb0 = ((const bf16x8*)wbm)[((GK) * 4 + 0) * 64 + lane]; \
    bf16x8 wb1 = ((const bf16x8*)wbm)[((GK) * 4 + 1) * 64 + lane]; \
    bf16x8 wb2 = ((const bf16x8*)wbm)[((GK) * 4 + 2) * 64 + lane]; \
    bf16x8 wb3 = ((const bf16x8*)wbm)[((GK) * 4 + 3) * 64 + lane]; \
    macc0 = __builtin_amdgcn_mfma_f32_16x16x32_bf16(a, wb0, macc0, 0, 0, 0); \
    macc1 = __builtin_amdgcn_mfma_f32_16x16x32_bf16(a, wb1, macc1, 0, 0, 0); \
    macc2 = __builtin_amdgcn_mfma_f32_16x16x32_bf16(a, wb2, macc2, 0, 0, 0); \
    macc3 = __builtin_amdgcn_mfma_f32_16x16x32_bf16(a, wb3, macc3, 0, 0, 0); \
}

// ---------------------------------------------------------------------------
// Kernel C: fully fused, 512 threads = 2 teams x 4 waves.
//   Team t owns offset-group g=t: phase O s-steps [t*9, t*9+9), phase M
//   gk in [t*9, t*9+9). Partials merged through LDS.
// ---------------------------------------------------------------------------
__global__ __launch_bounds__(512, 8)
void fused_kernel(const short* __restrict__ inpT,
                  const float* __restrict__ mask_in,
                  const short* __restrict__ wbs,
                  const short* __restrict__ wbm,
                  const float* __restrict__ sem_b,
                  const float* __restrict__ reg_w, const float* __restrict__ reg_b,
                  const float* __restrict__ m1_w, const float* __restrict__ m1_b,
                  const float* __restrict__ m2_b,
                  const float* __restrict__ bias,
                  float* __restrict__ out, float* __restrict__ um_out) {
    // sh: phase O/3 = red2[2][64][36] (18432 B) + ums (1024 B)
    //     phase M  = dout[64][68] (17408 B), overlaps red2 (dead after B2)
    __shared__ __align__(16) char sh[19456];
    float* red  = (float*)sh;                  // [team*2304 + px*36 + o]
    float* ums  = (float*)(sh + 18432);
    float* dout = (float*)sh;
    __shared__ float2 pxy[18 * 64];
    __shared__ float  dml[18 * 64];
    __shared__ float  umv[64];

    const int tid  = threadIdx.x;
    const int lane = tid & 63;
    const int w    = __builtin_amdgcn_readfirstlane(tid >> 6);   // 0..7
    const int team = w >> 2;                   // 0..1 == offset group
    const int wv   = w & 3;                    // M-tile within team
    const int n = lane & 15, q = lane >> 4;

    // XCD band swizzle: band = bid&7 -> contiguous 48-row y-band per XCD
    const int bid  = blockIdx.x;
    const int band = bid & 7;
    const int jb   = bid >> 3;                 // 0..143
    const int xt   = jb % 3;
    const int rr   = band * 48 + jb / 3;       // global row in [0, 384)
    const int y    = rr % H_;
    const int b    = rr / H_;

    const int xn = xt * PIX + wv * 16 + n;     // fragment pixel (M-row)

    // ====== phase O: sem(18)+m2(9) conv via MFMA, s split across teams ======
    f32x4 acc0 = {0.f, 0.f, 0.f, 0.f}, acc1 = {0.f, 0.f, 0.f, 0.f};
    for (int ss = 0; ss < 9; ++ss) {
        int s = team * 9 + ss;
        int t_ = s >> 1, h = s & 1;
        int dy = t_ / 3 - 1, dx = t_ % 3 - 1;
        int yy = y + dy, xx = xn + dx;
        bool vv = (yy >= 0 && yy < H_ && xx >= 0 && xx < W_);
        int yc = min(max(yy, 0), H_ - 1), xc = min(max(xx, 0), W_ - 1);
        bf16x8 a = *(const bf16x8*)&inpT[((size_t)(b * HW_ + yc * W_ + xc)) * 64 + h * 32 + q * 8];
        if (!vv) { a[0]=0;a[1]=0;a[2]=0;a[3]=0;a[4]=0;a[5]=0;a[6]=0;a[7]=0; }
        bf16x8 b0 = ((const bf16x8*)wbs)[(s * 2 + 0) * 64 + lane];
        bf16x8 b1 = ((const bf16x8*)wbs)[(s * 2 + 1) * 64 + lane];
        acc0 = __builtin_amdgcn_mfma_f32_16x16x32_bf16(a, b0, acc0, 0, 0, 0);
        acc1 = __builtin_amdgcn_mfma_f32_16x16x32_bf16(a, b1, acc1, 0, 0, 0);
    }
    #pragma unroll
    for (int r = 0; r < 4; ++r) {
        red[team * 2304 + (wv * 16 + q * 4 + r) * 36 + n]      = acc0[r];
        red[team * 2304 + (wv * 16 + q * 4 + r) * 36 + 16 + n] = acc1[r];
    }
    __syncthreads();   // B1

    // ====== phase 3 (team 0 only): finish offsets/modulation/umask ==========
    if (team == 0) {
        const int xl = xt * PIX + lane;
        const int pixl = y * W_ + xl;
        const bool vxm = xl > 0, vxp = (xl + 1) < W_;
        const bool vym = y > 0,  vyp = (y + 1) < H_;
        int g  = w >> 1;
        int k0 = (w & 1) ? 5 : 0;
        int k1 = (w & 1) ? 9 : 5;
        float off_[18], mm[9];
        if (g == 0) {
            const float* mbp = mask_in + (size_t)b * HW_ + pixl;
            float mv[9];
            mv[0] = (vym && vxm) ? mbp[-W_ - 1] : 0.f;
            mv[1] = vym ? mbp[-W_] : 0.f;
            mv[2] = (vym && vxp) ? mbp[-W_ + 1] : 0.f;
            mv[3] = vxm ? mbp[-1] : 0.f;
            mv[4] = mbp[0];
            mv[5] = vxp ? mbp[1] : 0.f;
            mv[6] = (vyp && vxm) ? mbp[W_ - 1] : 0.f;
            mv[7] = vyp ? mbp[W_] : 0.f;
            mv[8] = (vyp && vxp) ? mbp[W_ + 1] : 0.f;
            #pragma unroll
            for (int o = 0; o < 18; ++o) off_[o] = reg_b[o];
            #pragma unroll
            for (int o = 0; o < 9; ++o) mm[o] = m1_b[o];
            #pragma unroll
            for (int t = 0; t < 9; ++t) {
                float vt = mv[t];
                #pragma unroll
                for (int o = 0; o < 18; ++o) off_[o] += vt * reg_w[o * 9 + t];
                #pragma unroll
                for (int o = 0; o < 9; ++o) mm[o] += vt * m1_w[o * 9 + t];
            }
        } else {
            #pragma unroll
            for (int o = 0; o < 18; ++o)
                off_[o] = red[lane * 36 + o] + red[2304 + lane * 36 + o] + sem_b[o];
            #pragma unroll
            for (int o = 0; o < 9; ++o)
                mm[o] = red[lane * 36 + 18 + o] + red[2304 + lane * 36 + 18 + o] + m2_b[o];
        }

        const float* mb = mask_in + (size_t)b * HW_;
        float s_um = 0.f;
        #pragma unroll
        for (int k = 0; k < 9; ++k) {
            if (k < k0 || k >= k1) continue;
            float Y = off_[2 * k]     + (float)y  + (float)(k / 3 - 1);
            float X = off_[2 * k + 1] + (float)xl + (float)(k % 3 - 1);
            int gk = g * 9 + k;
            float2 xy; xy.x = Y; xy.y = X;
            pxy[gk * 64 + lane] = xy;
            dml[gk * 64 + lane] = 1.f / (1.f + expf(-mm[k]));
            float y0f = floorf(Y), x0f = floorf(X);
            int y0 = (int)y0f, x0 = (int)x0f;
            float ly = Y - y0f, lx = X - x0f;
            int y1 = y0 + 1, x1 = x0 + 1;
            bool vy0 = (y0 >= 0 && y0 < H_), vy1 = (y1 >= 0 && y1 < H_);
            bool vx0 = (x0 >= 0 && x0 < W_), vx1 = (x1 >= 0 && x1 < W_);
            int yc0 = min(max(y0, 0), H_ - 1), yc1 = min(max(y1, 0), H_ - 1);
            int xc0 = min(max(x0, 0), W_ - 1), xc1 = min(max(x1, 0), W_ - 1);
            float v00 = (vy0 && vx0) ? mb[yc0 * W_ + xc0] : 0.f;
            float v01 = (vy0 && vx1) ? mb[yc0 * W_ + xc1] : 0.f;
            float v10 = (vy1 && vx0) ? mb[yc1 * W_ + xc0] : 0.f;
            float v11 = (vy1 && vx1) ? mb[yc1 * W_ + xc1] : 0.f;
            s_um += v00 * (1.f - ly) * (1.f - lx) + v01 * (1.f - ly) * lx
                  + v10 * ly * (1.f - lx)        + v11 * ly * lx;
        }
        ums[w * 64 + lane] = s_um;
    }
    __syncthreads();   // B2
    if (w == 0) {
        float s = ums[lane] + ums[64 + lane] + ums[128 + lane] + ums[192 + lane];
        float u = fminf(fmaxf(64.f * s, 0.f), 1.f);
        um_out[(size_t)b * HW_ + y * W_ + xt * PIX + lane] = u;
        umv[lane] = u;
    }
    __syncthreads();   // B3

    // ====== phase M: main deformable conv, gk split across teams ============
    f32x4 macc0 = {0.f, 0.f, 0.f, 0.f};
    f32x4 macc1 = {0.f, 0.f, 0.f, 0.f};
    f32x4 macc2 = {0.f, 0.f, 0.f, 0.f};
    f32x4 macc3 = {0.f, 0.f, 0.f, 0.f};

    const int gk0  = team * 9;
    const int goff = team * CG_;
    for (int kk = 0; kk < KK_; ++kk) {
        MBODY(gk0 + kk, goff, wv)
    }

    // merge team partials through dout, then coalesced stores
    if (team == 1) {
        #pragma unroll
        for (int r = 0; r < 4; ++r) {
            dout[(wv * 16 + q * 4 + r) * 68 +  0 + n] = macc0[r];
            dout[(wv * 16 + q * 4 + r) * 68 + 16 + n] = macc1[r];
            dout[(wv * 16 + q * 4 + r) * 68 + 32 + n] = macc2[r];
            dout[(wv * 16 + q * 4 + r) * 68 + 48 + n] = macc3[r];
        }
    }
    __syncthreads();   // B4
    if (team == 0) {
        #pragma unroll
        for (int r = 0; r < 4; ++r) {
            dout[(wv * 16 + q * 4 + r) * 68 +  0 + n] += macc0[r];
            dout[(wv * 16 + q * 4 + r) * 68 + 16 + n] += macc1[r];
            dout[(wv * 16 + q * 4 + r) * 68 + 32 + n] += macc2[r];
            dout[(wv * 16 + q * 4 + r) * 68 + 48 + n] += macc3[r];
        }
    }
    __syncthreads();   // B5

    const int x   = xt * PIX + lane;
    const int pix = y * W_ + x;
    float u = umv[lane];
    const int ch0 = w * 8;
    float* ob = out + ((size_t)b * COUT + ch0) * HW_ + pix;
    const float* bs = bias + ch0;
    const float* dp = &dout[lane * 68 + ch0];
    #pragma unroll
    for (int o = 0; o < 8; ++o)
        ob[(size_t)o * HW_] = (dp[o] + bs[o]) * u;
}

// ---------------------------------------------------------------------------
extern "C" void kernel_launch(void* const* d_in, const int* in_sizes, int n_in,
                              void* d_out, int out_size, void* d_ws, size_t ws_size,
                              hipStream_t stream) {
    const float* input   = (const float*)d_in[0];
    const float* mask_in = (const float*)d_in[1];
    const float* weight  = (const float*)d_in[2];
    const float* bias    = (const float*)d_in[3];
    const float* sem_w   = (const float*)d_in[4];
    const float* sem_b   = (const float*)d_in[5];
    const float* reg_w   = (const float*)d_in[6];
    const float* reg_b   = (const float*)d_in[7];
    const float* m1_w    = (const float*)d_in[8];
    const float* m1_b    = (const float*)d_in[9];
    const float* m2_w    = (const float*)d_in[10];
    const float* m2_b    = (const float*)d_in[11];

    float* out = (float*)d_out;                        // (B,COUT,H,W)
    float* um  = out + (size_t)B_ * COUT * HW_;        // (B,1,H,W)

    // workspace (shorts): inpT (9.44 MB) + wbm + wbs
    short* inpT = (short*)d_ws;                        // B*HW*64
    short* wbm  = inpT + (size_t)B_ * HW_ * 64;        // 36,864
    short* wbs  = wbm + 18 * 4 * 64 * 8;               // 18,432

    prep_kernel<<<NB_NHWC + NB_WT, 256, 0, stream>>>(
        input, weight, sem_w, m2_w, inpT, wbm, wbs);
    fused_kernel<<<B_ * H_ * XT_, 512, 0, stream>>>(
        inpT, mask_in, wbs, wbm, sem_b, reg_w, reg_b, m1_w, m1_b, m2_b,
        bias, out, um);
}